// Round 8
// baseline (1107.388 us; speedup 1.0000x reference)
//
#include <hip/hip_runtime.h>
#include <stdint.h>

// RotEncoderMLP via Z4-spectral (DFT) decomposition of the C4 group convs.
//   x^[0]=x0+x1+x2+x3, x^[2]=x0-x1+x2-x3, x^[1]=ur+i*ui (ur=x0-x2, ui=x3-x1)
//   y^[w] = conj(W^[w]) . x^[w];  y[g] = (1/4)[y^0 + (-1)^g y^2 + 2 Re(y^1 i^g)]
// MACs: 16*HID^2 -> 6*HID^2.
// R7-R12: 256x256 8-phase pipelined GEMM (m201 template), LPT snake persistent
// blocks, fused single L3. Proven best: R10 = 990us (282us/chunk L2, conflicts 0).
// R13: FAILED - 32x32x16 MFMA tripped LDS bank conflicts (0 -> 2.36e7, +6%).
// R14: revert to R10's 16x16x32 GEMM verbatim; attack the 2.7x FETCH overfetch
//      (360 vs 134 MB ideal): C-writes thrash L3 and evict the A-chunk, so
//      stage loads become HBM misses that vmcnt(6) lookahead can't cover.
//      Fix: __builtin_nontemporal_store in the GEMM epilogue (nt flag, no
//      L2/L3 allocate) -> A stays L3-resident. Keep R13's float4 out_ep.

#define HID 2048
#define MROWS 10240

typedef float floatx4 __attribute__((ext_vector_type(4)));
typedef __bf16 bf16x8 __attribute__((ext_vector_type(8)));

__device__ __forceinline__ unsigned short f2bf(float f) {
  union { float f; unsigned int u; } v; v.f = f;
  unsigned int r = v.u + 0x7fffu + ((v.u >> 16) & 1u);  // RNE
  return (unsigned short)(r >> 16);
}
__device__ __forceinline__ float bf2f(unsigned short s) {
  union { unsigned int u; float f; } v; v.u = ((unsigned int)s) << 16;
  return v.f;
}

// ---------- spectral weight transform: w (4,NO,2048) f32 -> W0s, W2s (NO x 2048 bf16),
// Bc (2*NO x 4096 bf16) = [[Vr, -Vi],[Vi, Vr]] ----------
template <int NO>
__global__ __launch_bounds__(256) void wtrans_kernel(const float* __restrict__ w,
                                                     unsigned short* __restrict__ W0s,
                                                     unsigned short* __restrict__ W2s,
                                                     unsigned short* __restrict__ Bc) {
  int idx = blockIdx.x * 256 + threadIdx.x;       // i * 512 + j4
  int i = idx >> 9, j4 = idx & 511;
  const float4* wp = (const float4*)w;
  float4 w0 = wp[0 * NO * 512 + i * 512 + j4];
  float4 w1 = wp[1 * NO * 512 + i * 512 + j4];
  float4 w2 = wp[2 * NO * 512 + i * 512 + j4];
  float4 w3 = wp[3 * NO * 512 + i * 512 + j4];
  ushort4 s0, s2, vr, vi, nvi;
#define DO(c)                                        \
  s0.c = f2bf(w0.c + w1.c + w2.c + w3.c);            \
  s2.c = f2bf(w0.c - w1.c + w2.c - w3.c);            \
  vr.c = f2bf(w0.c - w2.c);                          \
  vi.c = f2bf(w1.c - w3.c);                          \
  nvi.c = f2bf(-(w1.c - w3.c));
  DO(x) DO(y) DO(z) DO(w)
#undef DO
  ((ushort4*)W0s)[i * 512 + j4] = s0;
  ((ushort4*)W2s)[i * 512 + j4] = s2;
  ((ushort4*)Bc)[i * 1024 + j4] = vr;            // row i:    [Vr | -Vi]
  ((ushort4*)Bc)[i * 1024 + 512 + j4] = nvi;
  ((ushort4*)Bc)[(NO + i) * 1024 + j4] = vi;     // row NO+i: [Vi |  Vr]
  ((ushort4*)Bc)[(NO + i) * 1024 + 512 + j4] = vr;
}

// ---------- orbit-stack + layer1 + relu + forward-DFT -> h1s bf16 (rows x 8192: [u0|u2|ur|ui]) ----------
__global__ __launch_bounds__(256) void layer1_kernel(const float* __restrict__ ins,
                                                     const float* __restrict__ w1,
                                                     const float* __restrict__ b1,
                                                     unsigned short* __restrict__ h1s,
                                                     int row0) {
  __shared__ float orbs[32][28];
  int t = threadIdx.x;
  int b0 = blockIdx.x * 32;            // chunk-local
  int i = blockIdx.y * 256 + t;
  if (t < 32) {
    const float* x = ins + (size_t)(row0 + b0 + t) * 25;
    float v[25];
#pragma unroll
    for (int p = 0; p < 25; ++p) v[p] = x[p];
    float* o = orbs[t];
    o[0] = v[12]; o[7] = v[12]; o[14] = v[12]; o[21] = v[12];
#pragma unroll
    for (int r = 0; r < 2; ++r)
#pragma unroll
      for (int c = 0; c < 3; ++c) {
        int m = 1 + r * 3 + c;
        o[m]      = v[r * 5 + c];
        o[7 + m]  = v[c * 5 + (4 - r)];
        o[14 + m] = v[(4 - r) * 5 + (4 - c)];
        o[21 + m] = v[(4 - c) * 5 + r];
      }
  }
  __syncthreads();
  float w[4][7];
#pragma unroll
  for (int r = 0; r < 4; ++r)
#pragma unroll
    for (int j = 0; j < 7; ++j) w[r][j] = w1[(r * HID + i) * 7 + j];
  float bias = b1[i];
  for (int s = 0; s < 32; ++s) {
    float a[4] = {bias, bias, bias, bias};
#pragma unroll
    for (int hh = 0; hh < 4; ++hh)
#pragma unroll
      for (int j = 0; j < 7; ++j) {
        float ov = orbs[s][hh * 7 + j];
#pragma unroll
        for (int g = 0; g < 4; ++g) a[g] += w[(hh - g) & 3][j] * ov;
      }
    float h0 = fmaxf(a[0], 0.f), h1 = fmaxf(a[1], 0.f);
    float h2 = fmaxf(a[2], 0.f), h3 = fmaxf(a[3], 0.f);
    size_t base = (size_t)(b0 + s) * 8192 + i;
    h1s[base]        = f2bf(h0 + h1 + h2 + h3);  // u0
    h1s[base + 2048] = f2bf(h0 - h1 + h2 - h3);  // u2
    h1s[base + 4096] = f2bf(h0 - h2);            // ur
    h1s[base + 6144] = f2bf(h3 - h1);            // ui
  }
}

// ---------- persistent 256x256 8-phase pipelined bf16 MFMA GEMM (16x16x32) ----------
// Work list (LPT, column-major): tiles [0,NTL) = long-K (nt = s2 + wt/MTN),
// [NTL,NT) = short-K. G blocks snake: pass p -> p*G+b (even) / (p+1)*G-1-b (odd).
// n-tile routing: nt<s1: B0,K=2048,aoff=0; nt<s2: B1,K=2048,aoff=2048; else B2,K=4096,aoff=4096.
// Output: bf16 to Cb (if non-null) else f32 to Cf — NONTEMPORAL stores (R14):
// C streams to HBM without L2/L3 allocate, preserving A-chunk L3 residency.
// LDS: row remap (half-tile = 2 contiguous 64-row global_load_lds sweeps);
// chunk swizzle ch ^= (lrow&7), source pre-swizzled, read ch = c ^ (lane15&7).
// Stage ring: P2:A0mh0 P3:B0nh0 P4:B0nh1 P5:A0mh1 P6:A1mh0 P7:B1nh0
// P8:B1nh1+A1mh1; counted vmcnt(6) at P4/P8 only; prologue 16 loads + vmcnt(8).

__global__ __launch_bounds__(512, 2) void gemm_spec(const unsigned short* __restrict__ A,
                                                    const unsigned short* __restrict__ B0,
                                                    const unsigned short* __restrict__ B1,
                                                    const unsigned short* __restrict__ B2,
                                                    float* __restrict__ Cf,
                                                    unsigned short* __restrict__ Cb,
                                                    int s1, int s2, int N0, int ldc,
                                                    int NT, int NTL, int MTN) {
  __shared__ __align__(16) unsigned short As[2][16384];
  __shared__ __align__(16) unsigned short Bs[2][16384];
  int tid = threadIdx.x;
  int wave = tid >> 6, lane = tid & 63;
  int lane15 = lane & 15, lane4 = lane >> 4, l7 = lane15 & 7;
  int wm = wave >> 2, wn = wave & 3;
  int wm64 = wm << 6, wn32 = wn << 5;

  int srow = tid >> 3;                               // 0..63 within a sweep
  int scol = ((tid & 7) ^ ((tid >> 3) & 7)) << 3;    // pre-swizzled source chunk
  int bs64 = (srow >> 5) << 6;                       // 0 or 64 (wave-uniform)

#define STA(buf, mh, kk)                                                                              \
  __builtin_amdgcn_global_load_lds(                                                                   \
      (const __attribute__((address_space(1))) void*)(Agb + (size_t)((mh) * 64) * 8192 + (kk)),       \
      (__attribute__((address_space(3))) void*)((char*)As[buf] + (mh) * 16384 + wave * 1024),         \
      16, 0, 0);                                                                                      \
  __builtin_amdgcn_global_load_lds(                                                                   \
      (const __attribute__((address_space(1))) void*)(Agb + (size_t)((mh) * 64 + 128) * 8192 + (kk)), \
      (__attribute__((address_space(3))) void*)((char*)As[buf] + (mh) * 16384 + 8192 + wave * 1024),  \
      16, 0, 0)

#define STB(buf, nh, kk)                                                                              \
  __builtin_amdgcn_global_load_lds(                                                                   \
      (const __attribute__((address_space(1))) void*)(Bgb + (size_t)(bs64 + (nh) * 32) * ldb + (kk)), \
      (__attribute__((address_space(3))) void*)((char*)Bs[buf] + (nh) * 16384 + wave * 1024),         \
      16, 0, 0);                                                                                      \
  __builtin_amdgcn_global_load_lds(                                                                   \
      (const __attribute__((address_space(1))) void*)(Bgb + (size_t)(bs64 + 128 + (nh) * 32) * ldb + (kk)), \
      (__attribute__((address_space(3))) void*)((char*)Bs[buf] + (nh) * 16384 + 8192 + wave * 1024),  \
      16, 0, 0)

#define RAF(buf, mh)                                                                                  \
  _Pragma("unroll") for (int mi_ = 0; mi_ < 4; ++mi_)                                                 \
  _Pragma("unroll") for (int ks_ = 0; ks_ < 2; ++ks_)                                                 \
      af[mi_][ks_] = *(const bf16x8*)((const char*)As[buf] +                                          \
          (((mh) * 128 + wm64 + mi_ * 16 + lane15) << 7) + (((ks_ * 4 + lane4) ^ l7) << 4))

#define RBF(dst, buf, nh)                                                                             \
  _Pragma("unroll") for (int ni_ = 0; ni_ < 2; ++ni_)                                                 \
  _Pragma("unroll") for (int ks_ = 0; ks_ < 2; ++ks_)                                                 \
      dst[ni_][ks_] = *(const bf16x8*)((const char*)Bs[buf] +                                         \
          (((nh) * 128 + wn32 + ni_ * 16 + lane15) << 7) + (((ks_ * 4 + lane4) ^ l7) << 4))

#define MM(mh, nh, bF)                                                                                \
  _Pragma("unroll") for (int mi_ = 0; mi_ < 4; ++mi_)                                                 \
  _Pragma("unroll") for (int ni_ = 0; ni_ < 2; ++ni_)                                                 \
  _Pragma("unroll") for (int ks_ = 0; ks_ < 2; ++ks_)                                                 \
      acc[(mh) * 4 + mi_][(nh) * 2 + ni_] = __builtin_amdgcn_mfma_f32_16x16x32_bf16(                  \
          af[mi_][ks_], bF[ni_][ks_], acc[(mh) * 4 + mi_][(nh) * 2 + ni_], 0, 0, 0)

#define BAR() __builtin_amdgcn_s_barrier()
#define LGKM0() asm volatile("s_waitcnt lgkmcnt(0)" ::: "memory")
#define LGKM8() asm volatile("s_waitcnt lgkmcnt(8)" ::: "memory")
#define VM6() asm volatile("s_waitcnt vmcnt(6)" ::: "memory")
#define VM8() asm volatile("s_waitcnt vmcnt(8)" ::: "memory")

  bf16x8 af[4][2], b0r[2][2], b1r[2][2];
  const floatx4 fz = {0.f, 0.f, 0.f, 0.f};
  floatx4 acc[8][4];

  int G = (int)gridDim.x;
  for (int pass = 0;; ++pass) {
    int base = pass * G;
    if (base >= NT) break;
    int wt = (pass & 1) ? (base + G - 1 - (int)blockIdx.x) : (base + (int)blockIdx.x);
    if (wt >= NT) continue;

    // column-major LPT decode (R10-measured)
    int mt, nt;
    if (wt < NTL) { int j = wt / MTN; nt = s2 + j; mt = wt - j * MTN; }
    else          { int w2_ = wt - NTL; int j = w2_ / MTN; nt = j; mt = w2_ - j * MTN; }
    int m0 = mt * 256;

    const unsigned short* Bp;
    int K, aoff, coff, nloc;
    if (nt < s1)      { Bp = B0; K = 2048; aoff = 0;    coff = 0;      nloc = nt * 256; }
    else if (nt < s2) { Bp = B1; K = 2048; aoff = 2048; coff = N0;     nloc = (nt - s1) * 256; }
    else              { Bp = B2; K = 4096; aoff = 4096; coff = 2 * N0; nloc = (nt - s2) * 256; }
    int ldb = K;

    const unsigned short* Agb = A + (size_t)(m0 + srow) * 8192 + aoff + scol;
    const unsigned short* Bgb = Bp + (size_t)(nloc + (srow & 31)) * ldb + scol;

#pragma unroll
    for (int a = 0; a < 8; ++a)
#pragma unroll
      for (int b = 0; b < 4; ++b) acc[a][b] = fz;

    // Prologue: T0 (buf0,k=0) then T1 (buf1,k=64), all 16 loads; vmcnt(8)
    // retires exactly T0's 8 (drains prev epilogue stores first, FIFO).
    STA(0, 0, 0); STB(0, 0, 0); STB(0, 1, 0); STA(0, 1, 0);
    STA(1, 0, 64); STB(1, 0, 64); STB(1, 1, 64); STA(1, 1, 64);
    VM8();
    BAR();

    for (int k0 = 0; k0 < K; k0 += 128) {
      // ---- P1: quad(0,0) of tile A (buf0)
      RAF(0, 0); RBF(b0r, 0, 0);
      LGKM8();
      BAR(); LGKM0();
      __builtin_amdgcn_s_setprio(1); MM(0, 0, b0r); __builtin_amdgcn_s_setprio(0);
      BAR();
      // ---- P2: quad(0,1); stage Ta'.A-mh0 (buf0, freed P1)
      RBF(b1r, 0, 1);
      STA(0, 0, k0 + 128);
      BAR(); LGKM0();
      __builtin_amdgcn_s_setprio(1); MM(0, 1, b1r); __builtin_amdgcn_s_setprio(0);
      BAR();
      // ---- P3: quad(1,0); stage Ta'.B-nh0 (freed P1)
      RAF(0, 1);
      STB(0, 0, k0 + 128);
      BAR(); LGKM0();
      __builtin_amdgcn_s_setprio(1); MM(1, 0, b0r); __builtin_amdgcn_s_setprio(0);
      BAR();
      // ---- P4: quad(1,1); stage Ta'.B-nh1 (freed P2); counted vmcnt
      // outstanding: prevP7(2)+prevP8(4)+P2..P4(6)=12 -> retire prevP7+prevP8
      STB(0, 1, k0 + 128);
      BAR(); LGKM0();
      __builtin_amdgcn_s_setprio(1); MM(1, 1, b1r); __builtin_amdgcn_s_setprio(0);
      VM6();
      BAR();
      // ---- P5: tile B (buf1) quad(0,0); stage Ta'.A-mh1 (freed P3)
      RAF(1, 0); RBF(b0r, 1, 0);
      STA(0, 1, k0 + 128);
      LGKM8();
      BAR(); LGKM0();
      __builtin_amdgcn_s_setprio(1); MM(0, 0, b0r); __builtin_amdgcn_s_setprio(0);
      BAR();
      // ---- P6: quad(0,1); stage Tb'.A-mh0 (buf1, freed P5)
      RBF(b1r, 1, 1);
      STA(1, 0, k0 + 192);
      BAR(); LGKM0();
      __builtin_amdgcn_s_setprio(1); MM(0, 1, b1r); __builtin_amdgcn_s_setprio(0);
      BAR();
      // ---- P7: quad(1,0); stage Tb'.B-nh0 (freed P5)
      RAF(1, 1);
      STB(1, 0, k0 + 192);
      BAR(); LGKM0();
      __builtin_amdgcn_s_setprio(1); MM(1, 0, b0r); __builtin_amdgcn_s_setprio(0);
      BAR();
      // ---- P8: quad(1,1); stage Tb'.B-nh1 (freed P6) + Tb'.A-mh1 (freed P7);
      // counted vmcnt: outstanding P5..P8(10) -> retire P5+P6
      STB(1, 1, k0 + 192);
      STA(1, 1, k0 + 192);
      BAR(); LGKM0();
      __builtin_amdgcn_s_setprio(1); MM(1, 1, b1r); __builtin_amdgcn_s_setprio(0);
      VM6();
      BAR();
    }
    asm volatile("s_waitcnt vmcnt(0)" ::: "memory");

    // epilogue: C/D layout col=lane&15, row=(lane>>4)*4+r; NONTEMPORAL stores
#pragma unroll
    for (int ni = 0; ni < 4; ++ni) {
      int col = coff + nloc + wn * 64 + (ni >> 1) * 32 + (ni & 1) * 16 + lane15;
#pragma unroll
      for (int mi = 0; mi < 8; ++mi) {
        int row = m0 + wm * 128 + (mi >> 2) * 64 + (mi & 3) * 16 + lane4 * 4;
        if (Cb) {
#pragma unroll
          for (int r = 0; r < 4; ++r)
            __builtin_nontemporal_store(f2bf(acc[mi][ni][r]),
                                        &Cb[(size_t)(row + r) * ldc + col]);
        } else {
#pragma unroll
          for (int r = 0; r < 4; ++r)
            __builtin_nontemporal_store(acc[mi][ni][r],
                                        &Cf[(size_t)(row + r) * ldc + col]);
        }
      }
    }
  }
#undef STA
#undef STB
#undef RAF
#undef RBF
#undef MM
#undef BAR
#undef LGKM0
#undef LGKM8
#undef VM6
#undef VM8
}

// ---------- inverse-DFT (+b2, /4) -> 4x LayerNorm -> relu -> forward-DFT -> out bf16 ----------
// NOTE: may be called with h1s == C2 (in-place): each row is fully register-
// resident between read and write (reads all precede the reduction barrier).
__global__ __launch_bounds__(256) void ln_spec_kernel(const unsigned short* C2,
                                                      const float* __restrict__ b2,
                                                      const float* __restrict__ ln_g,
                                                      const float* __restrict__ ln_b,
                                                      unsigned short* h1s) {
  int t = threadIdx.x;
  size_t base = (size_t)blockIdx.x * 8192;
  const ushort4* p = (const ushort4*)(C2 + base);   // planes: v0|v2|vr|vi (512 ushort4 each)
  const float4* bp2 = (const float4*)b2;
  float4 y[4][2];
  float s[4] = {0, 0, 0, 0}, q[4] = {0, 0, 0, 0};
#pragma unroll
  for (int hl = 0; hl < 2; ++hl) {
    int j = hl * 256 + t;
    ushort4 u0 = p[j], u2 = p[512 + j], ur = p[1024 + j], ui = p[1536 + j];
    float4 bb = bp2[j];
#define DO(c)                                                   \
  {                                                             \
    float v0 = bf2f(u0.c), v2 = bf2f(u2.c);                     \
    float vr = bf2f(ur.c), vi = bf2f(ui.c);                     \
    float e0 = 0.25f * (v0 + v2 + 2.f * vr) + bb.c;             \
    float e1 = 0.25f * (v0 - v2 - 2.f * vi) + bb.c;             \
    float e2 = 0.25f * (v0 + v2 - 2.f * vr) + bb.c;             \
    float e3 = 0.25f * (v0 - v2 + 2.f * vi) + bb.c;             \
    y[0][hl].c = e0; y[1][hl].c = e1; y[2][hl].c = e2; y[3][hl].c = e3; \
    s[0] += e0; q[0] += e0 * e0; s[1] += e1; q[1] += e1 * e1;   \
    s[2] += e2; q[2] += e2 * e2; s[3] += e3; q[3] += e3 * e3;   \
  }
    DO(x) DO(y) DO(z) DO(w)
#undef DO
  }
#pragma unroll
  for (int off = 32; off > 0; off >>= 1)
#pragma unroll
    for (int g = 0; g < 4; ++g) {
      s[g] += __shfl_down(s[g], off, 64);
      q[g] += __shfl_down(q[g], off, 64);
    }
  __shared__ float rs[4][4], rq[4][4];
  int w = t >> 6, l = t & 63;
  if (l == 0)
#pragma unroll
    for (int g = 0; g < 4; ++g) { rs[w][g] = s[g]; rq[w][g] = q[g]; }
  __syncthreads();
  float mean[4], rstd[4];
#pragma unroll
  for (int g = 0; g < 4; ++g) {
    float ss = rs[0][g] + rs[1][g] + rs[2][g] + rs[3][g];
    float qq = rq[0][g] + rq[1][g] + rq[2][g] + rq[3][g];
    mean[g] = ss * (1.f / HID);
    float var = qq * (1.f / HID) - mean[g] * mean[g];
    rstd[g] = rsqrtf(var + 1e-5f);
  }
  const float4* gp = (const float4*)ln_g;
  const float4* lbp = (const float4*)ln_b;
#pragma unroll
  for (int hl = 0; hl < 2; ++hl) {
    int j = hl * 256 + t;
    float4 gg = gp[j], lb = lbp[j];
    ushort4 o[4];
#define DO(c)                                                               \
  {                                                                         \
    float h0 = fmaxf((y[0][hl].c - mean[0]) * rstd[0] * gg.c + lb.c, 0.f);  \
    float h1 = fmaxf((y[1][hl].c - mean[1]) * rstd[1] * gg.c + lb.c, 0.f);  \
    float h2 = fmaxf((y[2][hl].c - mean[2]) * rstd[2] * gg.c + lb.c, 0.f);  \
    float h3 = fmaxf((y[3][hl].c - mean[3]) * rstd[3] * gg.c + lb.c, 0.f);  \
    o[0].c = f2bf(h0 + h1 + h2 + h3);                                       \
    o[1].c = f2bf(h0 - h1 + h2 - h3);                                       \
    o[2].c = f2bf(h0 - h2);                                                 \
    o[3].c = f2bf(h3 - h1);                                                 \
  }
    DO(x) DO(y) DO(z) DO(w)
#undef DO
    size_t ob = (size_t)blockIdx.x * 8192;
#pragma unroll
    for (int pl = 0; pl < 4; ++pl)
      ((ushort4*)(h1s + ob + pl * 2048))[j] = o[pl];
  }
}

// ---------- final inverse-DFT (+b3, /4): Z (rows x 2048 f32 [z0|z2|zr|zi]) -> out ----------
// float4-vectorized: thread -> (row, col-quad i4); 4 output segments per thread.
__global__ __launch_bounds__(256) void out_ep_kernel(const float* __restrict__ Z,
                                                     const float* __restrict__ b3,
                                                     float* __restrict__ out) {
  int e = blockIdx.x * 256 + threadIdx.x;
  int row = e >> 7, i4 = e & 127;
  const float4* Z4 = (const float4*)Z;
  const float4* b34 = (const float4*)b3;
  float4* o4 = (float4*)out;
  size_t base = (size_t)row * 512;   // in float4 units (2048 f32/row)
  float4 z0 = Z4[base + i4],       z2 = Z4[base + 128 + i4];
  float4 zr = Z4[base + 256 + i4], zi = Z4[base + 384 + i4];
  float4 bv = b34[i4];
  float4 e0, e1, e2, e3;
#define DO(c)                                     \
  e0.c = 0.25f * (z0.c + z2.c + 2.f * zr.c) + bv.c; \
  e1.c = 0.25f * (z0.c - z2.c - 2.f * zi.c) + bv.c; \
  e2.c = 0.25f * (z0.c + z2.c - 2.f * zr.c) + bv.c; \
  e3.c = 0.25f * (z0.c - z2.c + 2.f * zi.c) + bv.c;
  DO(x) DO(y) DO(z) DO(w)
#undef DO
  o4[base + i4]       = e0;
  o4[base + 128 + i4] = e1;
  o4[base + 256 + i4] = e2;
  o4[base + 384 + i4] = e3;
}

extern "C" void kernel_launch(void* const* d_in, const int* in_sizes, int n_in,
                              void* d_out, int out_size, void* d_ws, size_t ws_size,
                              hipStream_t stream) {
  const float* ins = (const float*)d_in[0];
  const float* w1  = (const float*)d_in[1];
  const float* b1  = (const float*)d_in[2];
  const float* w2  = (const float*)d_in[3];
  const float* b2  = (const float*)d_in[4];
  const float* w3  = (const float*)d_in[5];
  const float* b3  = (const float*)d_in[6];
  const float* lng = (const float*)d_in[7];
  const float* lnb = (const float*)d_in[8];
  float* out = (float*)d_out;
  char* ws = (char*)d_ws;

  // Spectral weights (bf16), persistent at base of ws.
  unsigned short* W0s2 = (unsigned short*)ws;
  unsigned short* W2s2 = W0s2 + 4194304;
  unsigned short* Bc2  = W2s2 + 4194304;
  unsigned short* W0s3 = Bc2 + 16777216;
  unsigned short* W2s3 = W0s3 + 1048576;
  unsigned short* Bc3  = W2s3 + 1048576;
  const size_t WT_BYTES = 62914560ull;
  char* chunk_base = ws + WT_BYTES;

  wtrans_kernel<2048><<<4096, 256, 0, stream>>>(w2, W0s2, W2s2, Bc2);
  wtrans_kernel<512><<<1024, 256, 0, stream>>>(w3, W0s3, W2s3, Bc3);

  const size_t H1_BYTES = (size_t)5120 * 8192 * 2;      // 84 MB (chunked h1s / Z full f32)
  const size_t H2_BYTES = (size_t)MROWS * 8192 * 2;     // 168 MB
  const size_t need_full = WT_BYTES + H1_BYTES + H2_BYTES + 4096;  // 315 MB (R9/R10-proven)

  if (ws_size >= need_full) {
    // ---- R10 flow (best measured): 2 chunks for L2; one full-rows L3 ----
    unsigned short* h1s = (unsigned short*)chunk_base;               // 5120 x 8192 bf16
    float*          Z   = (float*)chunk_base;                        // 10240 x 2048 f32 (alias)
    unsigned short* H2  = (unsigned short*)(chunk_base + H1_BYTES);  // 10240 x 8192 bf16
    const int Mc = 5120, MTN = Mc / 256;
    for (int c = 0; c < 2; ++c) {
      int row0 = c * Mc;
      unsigned short* H2c = H2 + (size_t)row0 * 8192;
      layer1_kernel<<<dim3(Mc / 32, 8), 256, 0, stream>>>(ins, w1, b1, h1s, row0);
      gemm_spec<<<256, 512, 0, stream>>>(h1s, W0s2, W2s2, Bc2, nullptr, H2c,
                                         8, 16, 2048, 8192, 32 * MTN, 16 * MTN, MTN);
      ln_spec_kernel<<<Mc, 256, 0, stream>>>(H2c, b2, lng, lnb, H2c);
    }
    {
      const int MT3 = MROWS / 256;
      gemm_spec<<<256, 512, 0, stream>>>(H2, W0s3, W2s3, Bc3, Z, nullptr,
                                         2, 4, 512, 2048, 8 * MT3, 4 * MT3, MT3);
      out_ep_kernel<<<MROWS / 2, 256, 0, stream>>>(Z, b3, out);
    }
  } else {
    // ---- fallback: chunked flow (persistent-snake GEMMs) ----
    static const int Pcand[8] = {1, 2, 4, 5, 8, 10, 20, 40};
    int P = 40;
    for (int pi = 0; pi < 8; ++pi) {
      size_t mc = (size_t)MROWS / Pcand[pi];
      size_t need = WT_BYTES + mc * 8192 * 2 * 2 + 4096;
      if (need <= ws_size) { P = Pcand[pi]; break; }
    }
    const int Mc = MROWS / P, MTN = Mc / 256;
    unsigned short* h1s = (unsigned short*)chunk_base;                     // Mc x 8192 bf16
    unsigned short* C2  = (unsigned short*)(chunk_base + (size_t)Mc * 8192 * 2);
    float*          Z   = (float*)C2;                                      // Mc x 2048 f32 (alias)
    for (int c = 0; c < P; ++c) {
      int row0 = c * Mc;
      layer1_kernel<<<dim3(Mc / 32, 8), 256, 0, stream>>>(ins, w1, b1, h1s, row0);
      gemm_spec<<<256, 512, 0, stream>>>(h1s, W0s2, W2s2, Bc2, nullptr, C2,
                                         8, 16, 2048, 8192, 32 * MTN, 16 * MTN, MTN);
      ln_spec_kernel<<<Mc, 256, 0, stream>>>(C2, b2, lng, lnb, h1s);
      gemm_spec<<<256, 512, 0, stream>>>(h1s, W0s3, W2s3, Bc3, Z, nullptr,
                                         2, 4, 512, 2048, 8 * MTN, 4 * MTN, MTN);
      out_ep_kernel<<<Mc / 2, 256, 0, stream>>>(Z, b3, out + (size_t)row0 * 2048);
    }
  }
}

// Round 9
// 1002.878 us; speedup vs baseline: 1.1042x; 1.1042x over previous
//
#include <hip/hip_runtime.h>
#include <stdint.h>

// RotEncoderMLP via Z4-spectral (DFT) decomposition of the C4 group convs.
// R15 (Gauss): complex product via 3 real products (t1=Vr*ur, t2=Vi*ui,
// t3=(Vr+Vi)*(ur+ui); vr=t1-t2, vi=t3-t1-t2): GEMM MACs 6*HID^2 -> 5*HID^2,
// ALL tiles uniform K=2048 (LPT deleted). Uneven chunks 6144/4096 rows make
// makespans 4u+3u (was 4u+4u): -1 unit ~= -70us. Planes: A/H = 5x2048
// [u0|u2|ur|ui|us]; C/Z = 5 planes [v0|v2|t1|t2|t3]. 8-phase ring, vmcnt
// ledger, LDS swizzle, 16x16x32 MFMA byte-identical to R10 (990us proven).
// ws: weights 50MB + h1s 126MB + H2 126MB = 304MB < 315MB (R9/R10-proven).
// R13 (32x32 mfma): bank conflicts. R14 (nt stores): FETCH unchanged ->
// A-eviction theory false; epilogue completion slowed prologue vmcnt. Reverted.

#define HID 2048
#define MROWS 10240
#define AW 10240  // A/H row width: 5 planes x 2048

typedef float floatx4 __attribute__((ext_vector_type(4)));
typedef __bf16 bf16x8 __attribute__((ext_vector_type(8)));

__device__ __forceinline__ unsigned short f2bf(float f) {
  union { float f; unsigned int u; } v; v.f = f;
  unsigned int r = v.u + 0x7fffu + ((v.u >> 16) & 1u);  // RNE
  return (unsigned short)(r >> 16);
}
__device__ __forceinline__ float bf2f(unsigned short s) {
  union { unsigned int u; float f; } v; v.u = ((unsigned int)s) << 16;
  return v.f;
}

// ---------- spectral weight transform: w (4,NO,2048) f32 -> Wb = 5 matrices
// (NO x 2048 bf16, contiguous): [S0 | S2 | VR | VI | VS=VR+VI] ----------
template <int NO>
__global__ __launch_bounds__(256) void wtrans_kernel(const float* __restrict__ w,
                                                     unsigned short* __restrict__ Wb) {
  int idx = blockIdx.x * 256 + threadIdx.x;       // i * 512 + j4
  int i = idx >> 9, j4 = idx & 511;
  const float4* wp = (const float4*)w;
  float4 w0 = wp[0 * NO * 512 + i * 512 + j4];
  float4 w1 = wp[1 * NO * 512 + i * 512 + j4];
  float4 w2 = wp[2 * NO * 512 + i * 512 + j4];
  float4 w3 = wp[3 * NO * 512 + i * 512 + j4];
  ushort4 s0, s2, vr, vi, vs;
#define DO(c)                                        \
  {                                                  \
    float vrf = w0.c - w2.c, vif = w1.c - w3.c;      \
    s0.c = f2bf(w0.c + w1.c + w2.c + w3.c);          \
    s2.c = f2bf(w0.c - w1.c + w2.c - w3.c);          \
    vr.c = f2bf(vrf);                                \
    vi.c = f2bf(vif);                                \
    vs.c = f2bf(vrf + vif);                          \
  }
  DO(x) DO(y) DO(z) DO(w)
#undef DO
  ushort4* O = (ushort4*)Wb;
  const int MS = NO * 512;  // matrix size in ushort4
  O[0 * MS + i * 512 + j4] = s0;
  O[1 * MS + i * 512 + j4] = s2;
  O[2 * MS + i * 512 + j4] = vr;
  O[3 * MS + i * 512 + j4] = vi;
  O[4 * MS + i * 512 + j4] = vs;
}

// ---------- orbit-stack + layer1 + relu + forward-DFT -> h1s bf16
// (rows x AW: [u0|u2|ur|ui|us]) ----------
__global__ __launch_bounds__(256) void layer1_kernel(const float* __restrict__ ins,
                                                     const float* __restrict__ w1,
                                                     const float* __restrict__ b1,
                                                     unsigned short* __restrict__ h1s,
                                                     int row0) {
  __shared__ float orbs[32][28];
  int t = threadIdx.x;
  int b0 = blockIdx.x * 32;            // chunk-local
  int i = blockIdx.y * 256 + t;
  if (t < 32) {
    const float* x = ins + (size_t)(row0 + b0 + t) * 25;
    float v[25];
#pragma unroll
    for (int p = 0; p < 25; ++p) v[p] = x[p];
    float* o = orbs[t];
    o[0] = v[12]; o[7] = v[12]; o[14] = v[12]; o[21] = v[12];
#pragma unroll
    for (int r = 0; r < 2; ++r)
#pragma unroll
      for (int c = 0; c < 3; ++c) {
        int m = 1 + r * 3 + c;
        o[m]      = v[r * 5 + c];
        o[7 + m]  = v[c * 5 + (4 - r)];
        o[14 + m] = v[(4 - r) * 5 + (4 - c)];
        o[21 + m] = v[(4 - c) * 5 + r];
      }
  }
  __syncthreads();
  float w[4][7];
#pragma unroll
  for (int r = 0; r < 4; ++r)
#pragma unroll
    for (int j = 0; j < 7; ++j) w[r][j] = w1[(r * HID + i) * 7 + j];
  float bias = b1[i];
  for (int s = 0; s < 32; ++s) {
    float a[4] = {bias, bias, bias, bias};
#pragma unroll
    for (int hh = 0; hh < 4; ++hh)
#pragma unroll
      for (int j = 0; j < 7; ++j) {
        float ov = orbs[s][hh * 7 + j];
#pragma unroll
        for (int g = 0; g < 4; ++g) a[g] += w[(hh - g) & 3][j] * ov;
      }
    float h0 = fmaxf(a[0], 0.f), h1 = fmaxf(a[1], 0.f);
    float h2 = fmaxf(a[2], 0.f), h3 = fmaxf(a[3], 0.f);
    float ur = h0 - h2, ui = h3 - h1;
    size_t base = (size_t)(b0 + s) * AW + i;
    h1s[base]        = f2bf(h0 + h1 + h2 + h3);  // u0
    h1s[base + 2048] = f2bf(h0 - h1 + h2 - h3);  // u2
    h1s[base + 4096] = f2bf(ur);                 // ur
    h1s[base + 6144] = f2bf(ui);                 // ui
    h1s[base + 8192] = f2bf(ur + ui);            // us
  }
}

// ---------- persistent 256x256 8-phase pipelined bf16 MFMA GEMM (16x16x32) ----------
// UNIFORM K=2048, 5 segments. n-tile nt: seg = nt/segN, nloc = (nt%segN)*256;
// B matrix = Bb + seg*N0*2048 (row-major N0 x 2048); aoff = seg*2048 (A plane);
// coff = seg*N0 (C plane). Work decode column-major (mt fastest within nt);
// G blocks snake: pass p -> p*G+b (even) / (p+1)*G-1-b (odd).
// LDS: row remap (half-tile = 2 contiguous 64-row global_load_lds sweeps);
// chunk swizzle ch ^= (lrow&7), source pre-swizzled, read ch = c ^ (lane15&7).
// Stage ring: P2:A0mh0 P3:B0nh0 P4:B0nh1 P5:A0mh1 P6:A1mh0 P7:B1nh0
// P8:B1nh1+A1mh1; counted vmcnt(6) at P4/P8 only; prologue 16 loads + vmcnt(8).
// Tail stages wrap k->0 (garbage, never consumed; counts == ledger).

__global__ __launch_bounds__(512, 2) void gemm_spec(const unsigned short* __restrict__ A,
                                                    const unsigned short* __restrict__ Bb,
                                                    float* __restrict__ Cf,
                                                    unsigned short* __restrict__ Cb,
                                                    int N0, int ldc,
                                                    int NT, int MTN, int segN) {
  __shared__ __align__(16) unsigned short As[2][16384];
  __shared__ __align__(16) unsigned short Bs[2][16384];
  int tid = threadIdx.x;
  int wave = tid >> 6, lane = tid & 63;
  int lane15 = lane & 15, lane4 = lane >> 4, l7 = lane15 & 7;
  int wm = wave >> 2, wn = wave & 3;
  int wm64 = wm << 6, wn32 = wn << 5;

  int srow = tid >> 3;                               // 0..63 within a sweep
  int scol = ((tid & 7) ^ ((tid >> 3) & 7)) << 3;    // pre-swizzled source chunk
  int bs64 = (srow >> 5) << 6;                       // 0 or 64 (wave-uniform)
  const int K = 2048, ldb = 2048;

#define STA(buf, mh, kk)                                                                              \
  __builtin_amdgcn_global_load_lds(                                                                   \
      (const __attribute__((address_space(1))) void*)(Agb + (size_t)((mh) * 64) * AW + (kk)),         \
      (__attribute__((address_space(3))) void*)((char*)As[buf] + (mh) * 16384 + wave * 1024),         \
      16, 0, 0);                                                                                      \
  __builtin_amdgcn_global_load_lds(                                                                   \
      (const __attribute__((address_space(1))) void*)(Agb + (size_t)((mh) * 64 + 128) * AW + (kk)),   \
      (__attribute__((address_space(3))) void*)((char*)As[buf] + (mh) * 16384 + 8192 + wave * 1024),  \
      16, 0, 0)

#define STB(buf, nh, kk)                                                                              \
  __builtin_amdgcn_global_load_lds(                                                                   \
      (const __attribute__((address_space(1))) void*)(Bgb + (size_t)(bs64 + (nh) * 32) * ldb + (kk)), \
      (__attribute__((address_space(3))) void*)((char*)Bs[buf] + (nh) * 16384 + wave * 1024),         \
      16, 0, 0);                                                                                      \
  __builtin_amdgcn_global_load_lds(                                                                   \
      (const __attribute__((address_space(1))) void*)(Bgb + (size_t)(bs64 + 128 + (nh) * 32) * ldb + (kk)), \
      (__attribute__((address_space(3))) void*)((char*)Bs[buf] + (nh) * 16384 + 8192 + wave * 1024),  \
      16, 0, 0)

#define RAF(buf, mh)                                                                                  \
  _Pragma("unroll") for (int mi_ = 0; mi_ < 4; ++mi_)                                                 \
  _Pragma("unroll") for (int ks_ = 0; ks_ < 2; ++ks_)                                                 \
      af[mi_][ks_] = *(const bf16x8*)((const char*)As[buf] +                                          \
          (((mh) * 128 + wm64 + mi_ * 16 + lane15) << 7) + (((ks_ * 4 + lane4) ^ l7) << 4))

#define RBF(dst, buf, nh)                                                                             \
  _Pragma("unroll") for (int ni_ = 0; ni_ < 2; ++ni_)                                                 \
  _Pragma("unroll") for (int ks_ = 0; ks_ < 2; ++ks_)                                                 \
      dst[ni_][ks_] = *(const bf16x8*)((const char*)Bs[buf] +                                         \
          (((nh) * 128 + wn32 + ni_ * 16 + lane15) << 7) + (((ks_ * 4 + lane4) ^ l7) << 4))

#define MM(mh, nh, bF)                                                                                \
  _Pragma("unroll") for (int mi_ = 0; mi_ < 4; ++mi_)                                                 \
  _Pragma("unroll") for (int ni_ = 0; ni_ < 2; ++ni_)                                                 \
  _Pragma("unroll") for (int ks_ = 0; ks_ < 2; ++ks_)                                                 \
      acc[(mh) * 4 + mi_][(nh) * 2 + ni_] = __builtin_amdgcn_mfma_f32_16x16x32_bf16(                  \
          af[mi_][ks_], bF[ni_][ks_], acc[(mh) * 4 + mi_][(nh) * 2 + ni_], 0, 0, 0)

#define BAR() __builtin_amdgcn_s_barrier()
#define LGKM0() asm volatile("s_waitcnt lgkmcnt(0)" ::: "memory")
#define LGKM8() asm volatile("s_waitcnt lgkmcnt(8)" ::: "memory")
#define VM6() asm volatile("s_waitcnt vmcnt(6)" ::: "memory")
#define VM8() asm volatile("s_waitcnt vmcnt(8)" ::: "memory")

  bf16x8 af[4][2], b0r[2][2], b1r[2][2];
  const floatx4 fz = {0.f, 0.f, 0.f, 0.f};
  floatx4 acc[8][4];

  int G = (int)gridDim.x;
  for (int pass = 0;; ++pass) {
    int base = pass * G;
    if (base >= NT) break;
    int wt = (pass & 1) ? (base + G - 1 - (int)blockIdx.x) : (base + (int)blockIdx.x);
    if (wt >= NT) continue;

    int nt = wt / MTN, mt = wt - nt * MTN;   // column-major (mt fastest)
    int m0 = mt * 256;
    int seg = nt / segN, nloc = (nt - seg * segN) * 256;
    const unsigned short* Bp = Bb + (size_t)seg * N0 * 2048;
    int aoff = seg * 2048, coff = seg * N0;

    const unsigned short* Agb = A + (size_t)(m0 + srow) * AW + aoff + scol;
    const unsigned short* Bgb = Bp + (size_t)(nloc + (srow & 31)) * ldb + scol;

#pragma unroll
    for (int a = 0; a < 8; ++a)
#pragma unroll
      for (int b = 0; b < 4; ++b) acc[a][b] = fz;

    // Prologue: T0 (buf0,k=0) then T1 (buf1,k=64), all 16 loads; vmcnt(8)
    // retires exactly T0's 8 (drains prev epilogue stores first, FIFO).
    STA(0, 0, 0); STB(0, 0, 0); STB(0, 1, 0); STA(0, 1, 0);
    STA(1, 0, 64); STB(1, 0, 64); STB(1, 1, 64); STA(1, 1, 64);
    VM8();
    BAR();

    for (int k0 = 0; k0 < K; k0 += 128) {
      int ka = k0 + 128; if (ka >= K) ka = 0;   // tail wrap: garbage, never
      int kb = k0 + 192; if (kb >= K) kb = 0;   // consumed; count unchanged
      // ---- P1: quad(0,0) of tile A (buf0)
      RAF(0, 0); RBF(b0r, 0, 0);
      LGKM8();
      BAR(); LGKM0();
      __builtin_amdgcn_s_setprio(1); MM(0, 0, b0r); __builtin_amdgcn_s_setprio(0);
      BAR();
      // ---- P2: quad(0,1); stage Ta'.A-mh0 (buf0, freed P1)
      RBF(b1r, 0, 1);
      STA(0, 0, ka);
      BAR(); LGKM0();
      __builtin_amdgcn_s_setprio(1); MM(0, 1, b1r); __builtin_amdgcn_s_setprio(0);
      BAR();
      // ---- P3: quad(1,0); stage Ta'.B-nh0 (freed P1)
      RAF(0, 1);
      STB(0, 0, ka);
      BAR(); LGKM0();
      __builtin_amdgcn_s_setprio(1); MM(1, 0, b0r); __builtin_amdgcn_s_setprio(0);
      BAR();
      // ---- P4: quad(1,1); stage Ta'.B-nh1 (freed P2); counted vmcnt
      // outstanding: prevP7(2)+prevP8(4)+P2..P4(6)=12 -> retire prevP7+prevP8
      STB(0, 1, ka);
      BAR(); LGKM0();
      __builtin_amdgcn_s_setprio(1); MM(1, 1, b1r); __builtin_amdgcn_s_setprio(0);
      VM6();
      BAR();
      // ---- P5: tile B (buf1) quad(0,0); stage Ta'.A-mh1 (freed P3)
      RAF(1, 0); RBF(b0r, 1, 0);
      STA(0, 1, ka);
      LGKM8();
      BAR(); LGKM0();
      __builtin_amdgcn_s_setprio(1); MM(0, 0, b0r); __builtin_amdgcn_s_setprio(0);
      BAR();
      // ---- P6: quad(0,1); stage Tb'.A-mh0 (buf1, freed P5)
      RBF(b1r, 1, 1);
      STA(1, 0, kb);
      BAR(); LGKM0();
      __builtin_amdgcn_s_setprio(1); MM(0, 1, b1r); __builtin_amdgcn_s_setprio(0);
      BAR();
      // ---- P7: quad(1,0); stage Tb'.B-nh0 (freed P5)
      RAF(1, 1);
      STB(1, 0, kb);
      BAR(); LGKM0();
      __builtin_amdgcn_s_setprio(1); MM(1, 0, b0r); __builtin_amdgcn_s_setprio(0);
      BAR();
      // ---- P8: quad(1,1); stage Tb'.B-nh1 (freed P6) + Tb'.A-mh1 (freed P7);
      // counted vmcnt: outstanding P5..P8(10) -> retire P5+P6
      STB(1, 1, kb);
      STA(1, 1, kb);
      BAR(); LGKM0();
      __builtin_amdgcn_s_setprio(1); MM(1, 1, b1r); __builtin_amdgcn_s_setprio(0);
      VM6();
      BAR();
    }
    asm volatile("s_waitcnt vmcnt(0)" ::: "memory");

    // epilogue: C/D layout col=lane&15, row=(lane>>4)*4+r
#pragma unroll
    for (int ni = 0; ni < 4; ++ni) {
      int col = coff + nloc + wn * 64 + (ni >> 1) * 32 + (ni & 1) * 16 + lane15;
#pragma unroll
      for (int mi = 0; mi < 8; ++mi) {
        int row = m0 + wm * 128 + (mi >> 2) * 64 + (mi & 3) * 16 + lane4 * 4;
        if (Cb) {
#pragma unroll
          for (int r = 0; r < 4; ++r)
            Cb[(size_t)(row + r) * ldc + col] = f2bf(acc[mi][ni][r]);
        } else {
#pragma unroll
          for (int r = 0; r < 4; ++r)
            Cf[(size_t)(row + r) * ldc + col] = acc[mi][ni][r];
        }
      }
    }
  }
#undef STA
#undef STB
#undef RAF
#undef RBF
#undef MM
#undef BAR
#undef LGKM0
#undef LGKM8
#undef VM6
#undef VM8
}

// ---------- Gauss combine + inverse-DFT (+b2,/4) -> 4x LayerNorm -> relu ->
// forward-DFT -> 5 planes bf16. In-place safe (reads precede barrier+writes).
// Input planes (ushort4 offsets, row width 2560 u4): v0@0 v2@512 t1@1024
// t2@1536 t3@2048. vr = t1-t2; vi = t3-t1-t2.
__global__ __launch_bounds__(256) void ln_spec_kernel(const unsigned short* C2,
                                                      const float* __restrict__ b2,
                                                      const float* __restrict__ ln_g,
                                                      const float* __restrict__ ln_b,
                                                      unsigned short* h1s) {
  int t = threadIdx.x;
  size_t base = (size_t)blockIdx.x * AW;
  const ushort4* p = (const ushort4*)(C2 + base);
  const float4* bp2 = (const float4*)b2;
  float4 y[4][2];
  float s[4] = {0, 0, 0, 0}, q[4] = {0, 0, 0, 0};
#pragma unroll
  for (int hl = 0; hl < 2; ++hl) {
    int j = hl * 256 + t;
    ushort4 u0 = p[j], u2 = p[512 + j];
    ushort4 t1 = p[1024 + j], t2v = p[1536 + j], t3 = p[2048 + j];
    float4 bb = bp2[j];
#define DO(c)                                                   \
  {                                                             \
    float v0 = bf2f(u0.c), v2 = bf2f(u2.c);                     \
    float T1 = bf2f(t1.c), T2 = bf2f(t2v.c), T3 = bf2f(t3.c);   \
    float vr = T1 - T2, vi = T3 - T1 - T2;                      \
    float e0 = 0.25f * (v0 + v2 + 2.f * vr) + bb.c;             \
    float e1 = 0.25f * (v0 - v2 - 2.f * vi) + bb.c;             \
    float e2 = 0.25f * (v0 + v2 - 2.f * vr) + bb.c;             \
    float e3 = 0.25f * (v0 - v2 + 2.f * vi) + bb.c;             \
    y[0][hl].c = e0; y[1][hl].c = e1; y[2][hl].c = e2; y[3][hl].c = e3; \
    s[0] += e0; q[0] += e0 * e0; s[1] += e1; q[1] += e1 * e1;   \
    s[2] += e2; q[2] += e2 * e2; s[3] += e3; q[3] += e3 * e3;   \
  }
    DO(x) DO(y) DO(z) DO(w)
#undef DO
  }
#pragma unroll
  for (int off = 32; off > 0; off >>= 1)
#pragma unroll
    for (int g = 0; g < 4; ++g) {
      s[g] += __shfl_down(s[g], off, 64);
      q[g] += __shfl_down(q[g], off, 64);
    }
  __shared__ float rs[4][4], rq[4][4];
  int w = t >> 6, l = t & 63;
  if (l == 0)
#pragma unroll
    for (int g = 0; g < 4; ++g) { rs[w][g] = s[g]; rq[w][g] = q[g]; }
  __syncthreads();
  float mean[4], rstd[4];
#pragma unroll
  for (int g = 0; g < 4; ++g) {
    float ss = rs[0][g] + rs[1][g] + rs[2][g] + rs[3][g];
    float qq = rq[0][g] + rq[1][g] + rq[2][g] + rq[3][g];
    mean[g] = ss * (1.f / HID);
    float var = qq * (1.f / HID) - mean[g] * mean[g];
    rstd[g] = rsqrtf(var + 1e-5f);
  }
  const float4* gp = (const float4*)ln_g;
  const float4* lbp = (const float4*)ln_b;
#pragma unroll
  for (int hl = 0; hl < 2; ++hl) {
    int j = hl * 256 + t;
    float4 gg = gp[j], lb = lbp[j];
    ushort4 o[5];
#define DO(c)                                                               \
  {                                                                         \
    float h0 = fmaxf((y[0][hl].c - mean[0]) * rstd[0] * gg.c + lb.c, 0.f);  \
    float h1 = fmaxf((y[1][hl].c - mean[1]) * rstd[1] * gg.c + lb.c, 0.f);  \
    float h2 = fmaxf((y[2][hl].c - mean[2]) * rstd[2] * gg.c + lb.c, 0.f);  \
    float h3 = fmaxf((y[3][hl].c - mean[3]) * rstd[3] * gg.c + lb.c, 0.f);  \
    float our = h0 - h2, oui = h3 - h1;                                     \
    o[0].c = f2bf(h0 + h1 + h2 + h3);                                       \
    o[1].c = f2bf(h0 - h1 + h2 - h3);                                       \
    o[2].c = f2bf(our);                                                     \
    o[3].c = f2bf(oui);                                                     \
    o[4].c = f2bf(our + oui);                                               \
  }
    DO(x) DO(y) DO(z) DO(w)
#undef DO
    unsigned short* hp = h1s + base;
#pragma unroll
    for (int pl = 0; pl < 5; ++pl)
      ((ushort4*)hp)[pl * 512 + j] = o[pl];
  }
}

// ---------- final Gauss combine + inverse-DFT (+b3, /4) ----------
// Z row = 2560 f32 = 640 float4: planes z0@0 z2@128 t1@256 t2@384 t3@512 (f4).
// out row = 2048 f32 = 512 float4: e0@0 e1@128 e2@256 e3@384.
__global__ __launch_bounds__(256) void out_ep_kernel(const float* __restrict__ Z,
                                                     const float* __restrict__ b3,
                                                     float* __restrict__ out) {
  int e = blockIdx.x * 256 + threadIdx.x;
  int row = e >> 7, i4 = e & 127;
  const float4* Z4 = (const float4*)Z;
  const float4* b34 = (const float4*)b3;
  float4* o4 = (float4*)out;
  size_t zb = (size_t)row * 640, ob = (size_t)row * 512;
  float4 z0 = Z4[zb + i4],       z2 = Z4[zb + 128 + i4];
  float4 T1 = Z4[zb + 256 + i4], T2 = Z4[zb + 384 + i4], T3 = Z4[zb + 512 + i4];
  float4 bv = b34[i4];
  float4 e0, e1, e2, e3;
#define DO(c)                                       \
  {                                                 \
    float zr = T1.c - T2.c, zi = T3.c - T1.c - T2.c; \
    e0.c = 0.25f * (z0.c + z2.c + 2.f * zr) + bv.c;  \
    e1.c = 0.25f * (z0.c - z2.c - 2.f * zi) + bv.c;  \
    e2.c = 0.25f * (z0.c + z2.c - 2.f * zr) + bv.c;  \
    e3.c = 0.25f * (z0.c - z2.c + 2.f * zi) + bv.c;  \
  }
  DO(x) DO(y) DO(z) DO(w)
#undef DO
  o4[ob + i4]       = e0;
  o4[ob + 128 + i4] = e1;
  o4[ob + 256 + i4] = e2;
  o4[ob + 384 + i4] = e3;
}

extern "C" void kernel_launch(void* const* d_in, const int* in_sizes, int n_in,
                              void* d_out, int out_size, void* d_ws, size_t ws_size,
                              hipStream_t stream) {
  const float* ins = (const float*)d_in[0];
  const float* w1  = (const float*)d_in[1];
  const float* b1  = (const float*)d_in[2];
  const float* w2  = (const float*)d_in[3];
  const float* b2  = (const float*)d_in[4];
  const float* w3  = (const float*)d_in[5];
  const float* b3  = (const float*)d_in[6];
  const float* lng = (const float*)d_in[7];
  const float* lnb = (const float*)d_in[8];
  float* out = (float*)d_out;
  char* ws = (char*)d_ws;

  // Weights: Wb2 = 5 x (2048x2048) bf16 = 40 MB; Wb3 = 5 x (512x2048) = 10 MB.
  unsigned short* Wb2 = (unsigned short*)ws;
  unsigned short* Wb3 = Wb2 + 5u * 2048 * 2048;
  const size_t WT_BYTES = (5ull * 2048 * 2048 + 5ull * 512 * 2048) * 2;  // 50 MB
  char* chunk_base = ws + WT_BYTES;

  wtrans_kernel<2048><<<4096, 256, 0, stream>>>(w2, Wb2);
  wtrans_kernel<512><<<1024, 256, 0, stream>>>(w3, Wb3);

  const size_t H1MAX = (size_t)6144 * AW * 2;   // 126 MB (chunk h1s / H2; Z aliases h1s)
  const size_t need = WT_BYTES + 2 * H1MAX + 4096;  // ~304 MB < proven 315 MB

  unsigned short* h1s = (unsigned short*)chunk_base;
  unsigned short* H2  = (unsigned short*)(chunk_base + H1MAX);
  float*          Z   = (float*)chunk_base;     // Mc x 2560 f32 (aliases h1s; dead then)

  if (ws_size >= need) {
    // Uneven chunks 6144/4096: L2 makespans 4u+3u (960/640 uniform tiles).
    const int r0s[2] = {0, 6144};
    const int mcs[2] = {6144, 4096};
    for (int c = 0; c < 2; ++c) {
      int row0 = r0s[c], Mc = mcs[c], MTN = Mc / 256;
      layer1_kernel<<<dim3(Mc / 32, 8), 256, 0, stream>>>(ins, w1, b1, h1s, row0);
      // L2: 5 segs x 8 n-tiles x MTN, all K=2048 -> H2 (bf16, ldc=AW)
      gemm_spec<<<256, 512, 0, stream>>>(h1s, Wb2, nullptr, H2,
                                         2048, AW, 40 * MTN, MTN, 8);
      ln_spec_kernel<<<Mc, 256, 0, stream>>>(H2, b2, lng, lnb, H2);
      // L3: 5 segs x 2 n-tiles x MTN -> Z (f32, ldc=2560)
      gemm_spec<<<256, 512, 0, stream>>>(H2, Wb3, Z, nullptr,
                                         512, 2560, 10 * MTN, MTN, 2);
      out_ep_kernel<<<Mc / 2, 256, 0, stream>>>(Z, b3, out + (size_t)row0 * 2048);
    }
  } else {
    // Fallback: 5 chunks of 2048 rows (needs 50 + 2x42 = 134 MB).
    for (int c = 0; c < 5; ++c) {
      int row0 = c * 2048, Mc = 2048, MTN = 8;
      unsigned short* H2c = (unsigned short*)(chunk_base + (size_t)Mc * AW * 2);
      float* Zc = (float*)chunk_base;
      layer1_kernel<<<dim3(Mc / 32, 8), 256, 0, stream>>>(ins, w1, b1, h1s, row0);
      gemm_spec<<<256, 512, 0, stream>>>(h1s, Wb2, nullptr, H2c,
                                         2048, AW, 40 * MTN, MTN, 8);
      ln_spec_kernel<<<Mc, 256, 0, stream>>>(H2c, b2, lng, lnb, H2c);
      gemm_spec<<<256, 512, 0, stream>>>(H2c, Wb3, Zc, nullptr,
                                         512, 2560, 10 * MTN, MTN, 2);
      out_ep_kernel<<<Mc / 2, 256, 0, stream>>>(Zc, b3, out + (size_t)row0 * 2048);
    }
  }
}